// Round 6
// baseline (307.911 us; speedup 1.0000x reference)
//
#include <hip/hip_runtime.h>

// out = X · M,  M = (W^T W)/32 (symmetric 1024x1024)
// X: 65536x1024 fp32.  W: 1024x1024 fp32.  out: 65536x1024 fp32.
// K1: compute_M (VALU outer-product, 256 blocks)
// K2: gemm_xm — 256x128 tile, BK=32, 8 waves (4x2, wave tile 64x64),
//     A: fp32 asm-loads + in-reg cvt + swizzled ds_write, 2-buf
//     B: global_load_lds, 3-buf
//     56 KB LDS -> 2 blocks/CU. Race-safe wait discipline:
//       top-of-iter VMC(1)  = register dep (cvt inputs), per-wave only
//       end-of-iter VMC(5)->BAR = cross-wave B-tile guarantee (VMC before
//       barrier is the ONLY cross-wave-safe pattern; R5's top-only VMC raced)

typedef unsigned short u16;
typedef unsigned int u32;
typedef __bf16 bf16x8 __attribute__((ext_vector_type(8)));
typedef float f32x4 __attribute__((ext_vector_type(4)));

#define BAR() __builtin_amdgcn_s_barrier()
#define LGKM0() asm volatile("s_waitcnt lgkmcnt(0)" ::: "memory")
#define VMC(n) asm volatile("s_waitcnt vmcnt(" #n ")" ::: "memory")
#define SCHED0() __builtin_amdgcn_sched_barrier(0)

__device__ __forceinline__ u16 f2bf(float f) {  // RNE fp32->bf16
  u32 u = __float_as_uint(f);
  u += 0x7fffu + ((u >> 16) & 1u);
  return (u16)(u >> 16);
}

__device__ __forceinline__ void gload_lds16(const void* g, void* l) {
  __builtin_amdgcn_global_load_lds((const __attribute__((address_space(1))) u32*)g,
                                   (__attribute__((address_space(3))) u32*)l,
                                   16, 0, 0);
}

__device__ __forceinline__ void load2x16(const float* p, f32x4& a, f32x4& b) {
  asm volatile("global_load_dwordx4 %0, %2, off\n\t"
               "global_load_dwordx4 %1, %2, off offset:16"
               : "=&v"(a), "=&v"(b)
               : "v"(p)
               : "memory");
}

__device__ __forceinline__ bf16x8 cvt8(f32x4 a, f32x4 b) {
  bf16x8 h;
  h[0] = (__bf16)a[0]; h[1] = (__bf16)a[1]; h[2] = (__bf16)a[2]; h[3] = (__bf16)a[3];
  h[4] = (__bf16)b[0]; h[5] = (__bf16)b[1]; h[6] = (__bf16)b[2]; h[7] = (__bf16)b[3];
  return h;
}

// ---------------- K1: M = (W^T W)/32, 64x64 tile per block --------------------
__global__ __launch_bounds__(256) void compute_M(const float* __restrict__ W,
                                                 u16* __restrict__ Mb) {
  __shared__ float w1[32][64];
  __shared__ float w2[32][64];
  const int t = threadIdx.x;
  const int i0 = blockIdx.y * 64;
  const int j0 = blockIdx.x * 64;
  const int tx = t & 15, ty = t >> 4;
  float acc[4][4] = {};
  for (int u0 = 0; u0 < 1024; u0 += 32) {
    __syncthreads();
#pragma unroll
    for (int p = 0; p < 2; ++p) {
      int idx = p * 256 + t;
      int lu = idx >> 4, lc = (idx & 15) * 4;
      *(float4*)&w1[lu][lc] = *(const float4*)(W + (size_t)(u0 + lu) * 1024 + i0 + lc);
      *(float4*)&w2[lu][lc] = *(const float4*)(W + (size_t)(u0 + lu) * 1024 + j0 + lc);
    }
    __syncthreads();
#pragma unroll 8
    for (int u = 0; u < 32; ++u) {
      float4 a = *(const float4*)&w1[u][ty * 4];
      float4 b = *(const float4*)&w2[u][tx * 4];
      float av[4] = {a.x, a.y, a.z, a.w};
      float bv[4] = {b.x, b.y, b.z, b.w};
#pragma unroll
      for (int e = 0; e < 4; ++e)
#pragma unroll
        for (int f = 0; f < 4; ++f)
          acc[e][f] += av[e] * bv[f];
    }
  }
  const float s = 0.03125f;
#pragma unroll
  for (int e = 0; e < 4; ++e) {
    ushort4 v;
    v.x = f2bf(acc[e][0] * s);
    v.y = f2bf(acc[e][1] * s);
    v.z = f2bf(acc[e][2] * s);
    v.w = f2bf(acc[e][3] * s);
    *(ushort4*)(Mb + (size_t)(i0 + ty * 4 + e) * 1024 + j0 + tx * 4) = v;
  }
}

// ---------------- K2: 2-blocks/CU deep-pipelined GEMM -------------------------
// Issue order per iter j<=29: [f_{j+2} x4][B_{j+2} x1].
// Invariant at iter-j top (after prev closing BAR): outstanding = [f_{j+1}(4), B_{j+1}].
//   VMC(1) forces f_{j+1} (cvt regs, per-wave dep). leaves B_{j+1}.
// Invariant at iter-j end: outstanding = [B_{j+1}, f_{j+2}(4), B_{j+2}].
//   VMC(5) forces B_{j+1}; closing BAR makes it visible to ALL waves before
//   iter j+1's ds_reads. j==30: VMC(0) (B_31 tail). j==31: none.
// Buffers: read bufA=j&1 / bufB=j%3; cvt writes bufA[(j+1)&1] (prior readers
// drained pre-LGKM0 of iter j-1); gload writes bufB[(j+2)%3] (readers at j-1
// drained likewise; write cannot land before its issue at iter j).
__global__ __launch_bounds__(512, 4) void gemm_xm(const float* __restrict__ X,
                                                  const u16* __restrict__ Mb,
                                                  float* __restrict__ out) {
  __shared__ u16 lA[2][8192];  // 2 bufs x 256 rows x 32 bf16 = 32 KB
  __shared__ u16 lB[3][4096];  // 3 bufs x 128 rows x 32 bf16 = 24 KB

  const int p = blockIdx.x;                  // nwg = 2048 (%8==0)
  const int wg = (p & 7) * 256 + (p >> 3);   // chunked XCD swizzle
  const int bm = wg >> 3;                    // 0..255
  const int bn = wg & 7;                     // 0..7 (A-panel shared by 8 on XCD)
  const size_t r0 = (size_t)bm * 256;
  const int c0 = bn * 128;

  const int t = threadIdx.x;
  const int lane = t & 63;
  const int w = t >> 6;
  const int wr = w >> 1, wc = w & 1;         // 4x2 wave grid, wave tile 64x64
  const int fr = lane & 15;
  const int kc = lane >> 4;

  const int srow = t >> 2;                   // 0..127
  const int scl = t & 3;
  const int csw = scl ^ ((srow >> 1) & 3);   // swizzled chunk
  const float* aLo = X + (r0 + srow) * 1024 + scl * 8;
  const float* aHi = X + (r0 + 128 + srow) * 1024 + scl * 8;
  u16* wLo = &lA[0][srow * 32 + csw * 8];
  u16* wHi = &lA[0][(srow + 128) * 32 + csw * 8];
  const u16* gB = Mb + (size_t)(c0 + srow) * 1024 + csw * 8;  // inverse-swz src
  const int slB = w * 512;                   // wave-uniform u16 slot base in lB buf

  f32x4 acc[4][4] = {};
  f32x4 pfa, pfb, pfc, pfd;
  f32x4 q0a, q0b, q0c, q0d;

  // ---- prologue: issue f0(4), f1(4)->pf, B0, B1; VMC(1) forces f0,f1,B0 ----
  load2x16(aLo, q0a, q0b);
  load2x16(aHi, q0c, q0d);
  load2x16(aLo + 32, pfa, pfb);
  load2x16(aHi + 32, pfc, pfd);
  gload_lds16(gB, (void*)&lB[0][slB]);
  gload_lds16(gB + 32, (void*)&lB[1][slB]);
  VMC(1);   // forces f0 (cvt now), f1 (pf), AND B0 (read at iter 0); leaves B1
  SCHED0();
  *(bf16x8*)(wLo) = cvt8(q0a, q0b);
  *(bf16x8*)(wHi) = cvt8(q0c, q0d);
  LGKM0();
  BAR();    // cross-wave: f0-cvt + B0 visible to all

  int rbB = 0, wbB = 2;  // j%3 and (j+2)%3
  for (int j = 0; j < 32; ++j) {
    const u16* bA = &lA[j & 1][0];
    const u16* bB = &lB[rbB][0];

    // top: register dep only (f_{j+1} for cvt); B_{j+1} stays in flight
    VMC(1);
    SCHED0();
    if (j <= 30) {
      const int ab = ((j + 1) & 1) * 8192;
      *(bf16x8*)(wLo + ab) = cvt8(pfa, pfb);
      *(bf16x8*)(wHi + ab) = cvt8(pfc, pfd);
    }
    bf16x8 af[4], bf[4];
#pragma unroll
    for (int m = 0; m < 4; ++m) {
      const int row = wr * 64 + m * 16 + fr;
      const int cs = kc ^ ((row >> 1) & 3);
      af[m] = *(const bf16x8*)&bA[row * 32 + cs * 8];
    }
#pragma unroll
    for (int n = 0; n < 4; ++n) {
      const int row = wc * 64 + n * 16 + fr;
      const int cs = kc ^ ((row >> 1) & 3);
      bf[n] = *(const bf16x8*)&bB[row * 32 + cs * 8];
    }
    if (j <= 29) {  // issue kt j+2: fp32 FIRST (vmcnt order), then B gload
      load2x16(aLo + (j + 2) * 32, pfa, pfb);
      load2x16(aHi + (j + 2) * 32, pfc, pfd);
      gload_lds16(gB + (j + 2) * 32, (void*)&lB[wbB][slB]);
    }
    BAR();
    LGKM0();
    SCHED0();
    __builtin_amdgcn_s_setprio(1);
#pragma unroll
    for (int m = 0; m < 4; ++m)
#pragma unroll
      for (int n = 0; n < 4; ++n)
        acc[m][n] = __builtin_amdgcn_mfma_f32_16x16x32_bf16(af[m], bf[n],
                                                            acc[m][n], 0, 0, 0);
    __builtin_amdgcn_s_setprio(0);
    // end: cross-wave B guarantee — VMC BEFORE the closing barrier
    if (j <= 29) {
      VMC(5);   // outstanding [B_{j+1}, f_{j+2}x4, B_{j+2}] -> forces B_{j+1}
    } else if (j == 30) {
      VMC(0);   // forces B_31
    }
    SCHED0();
    BAR();
    rbB = (rbB == 2) ? 0 : rbB + 1;
    wbB = (wbB == 2) ? 0 : wbB + 1;
  }

  // ---- epilogue: C layout col=lane&15, row=(lane>>4)*4+reg ----
  const int ocol = lane & 15;
  const int orow = (lane >> 4) * 4;
#pragma unroll
  for (int m = 0; m < 4; ++m) {
    const size_t rbase = (r0 + wr * 64 + m * 16 + orow) * 1024;
#pragma unroll
    for (int n = 0; n < 4; ++n) {
      float* o = out + rbase + (c0 + wc * 64 + n * 16 + ocol);
      o[0] = acc[m][n][0];
      o[1024] = acc[m][n][1];
      o[2048] = acc[m][n][2];
      o[3072] = acc[m][n][3];
    }
  }
}

extern "C" void kernel_launch(void* const* d_in, const int* in_sizes, int n_in,
                              void* d_out, int out_size, void* d_ws, size_t ws_size,
                              hipStream_t stream) {
  const float* X = (const float*)d_in[0];
  const float* W = (const float*)d_in[1];
  float* out = (float*)d_out;
  u16* Mb = (u16*)d_ws;  // 2 MB scratch

  compute_M<<<dim3(16, 16), 256, 0, stream>>>(W, Mb);
  gemm_xm<<<2048, 512, 0, stream>>>(X, Mb, out);
}

// Round 7
// 267.560 us; speedup vs baseline: 1.1508x; 1.1508x over previous
//
#include <hip/hip_runtime.h>

// out = X · M,  M = (W^T W)/32 (symmetric 1024x1024)
// X: 65536x1024 fp32.  W: 1024x1024 fp32.  out: 65536x1024 fp32.
// K1: compute_M (proven VALU outer-product, 256 blocks, ~30us)
// K2: gemm8p — 8-phase 256x256 tile, BK=64, 8 waves (2Mx4N, wave tile 128x64),
//   8 half-tile LDS slots (128 KB ring, slot = stream mod 8, K-half phases):
//     slots 0-3: kt even {A-kh0, B-kh0, A-kh1, B-kh1}; 4-7: kt odd.
//   A: fp32 asm loads at even phases -> cvt+swizzled ds_write 4 phases later
//      (2 pending reg sets); B: global_load_lds (pre-swizzled src, linear dest).
//   Uniform s_waitcnt vmcnt(6) at every odd-phase end BEFORE the closing
//   barrier (cross-wave-safe). Ledger-verified slot lifetimes:
//     overwrite at phase p targets a slot last read <= p-1 (reader LGKM0 +
//     barrier intervene); every load forced >= 1 barrier before its readers.

typedef unsigned short u16;
typedef unsigned int u32;
typedef __bf16 bf16x8 __attribute__((ext_vector_type(8)));
typedef float f32x4 __attribute__((ext_vector_type(4)));

#define BAR() __builtin_amdgcn_s_barrier()
#define LGKM0() asm volatile("s_waitcnt lgkmcnt(0)" ::: "memory")
#define VMC(n) asm volatile("s_waitcnt vmcnt(" #n ")" ::: "memory")
#define SCHED0() __builtin_amdgcn_sched_barrier(0)

__device__ __forceinline__ u16 f2bf(float f) {  // RNE fp32->bf16
  u32 u = __float_as_uint(f);
  u += 0x7fffu + ((u >> 16) & 1u);
  return (u16)(u >> 16);
}

__device__ __forceinline__ void gload_lds16(const void* g, void* l) {
  __builtin_amdgcn_global_load_lds((const __attribute__((address_space(1))) u32*)g,
                                   (__attribute__((address_space(3))) u32*)l,
                                   16, 0, 0);
}

__device__ __forceinline__ void load2x16(const float* p, f32x4& a, f32x4& b) {
  asm volatile("global_load_dwordx4 %0, %2, off\n\t"
               "global_load_dwordx4 %1, %2, off offset:16"
               : "=&v"(a), "=&v"(b)
               : "v"(p)
               : "memory");
}

__device__ __forceinline__ bf16x8 cvt8(f32x4 a, f32x4 b) {
  bf16x8 h;
  h[0] = (__bf16)a[0]; h[1] = (__bf16)a[1]; h[2] = (__bf16)a[2]; h[3] = (__bf16)a[3];
  h[4] = (__bf16)b[0]; h[5] = (__bf16)b[1]; h[6] = (__bf16)b[2]; h[7] = (__bf16)b[3];
  return h;
}

// ---------------- K1: M = (W^T W)/32, 64x64 tile per block --------------------
__global__ __launch_bounds__(256) void compute_M(const float* __restrict__ W,
                                                 u16* __restrict__ Mb) {
  __shared__ float w1[32][64];
  __shared__ float w2[32][64];
  const int t = threadIdx.x;
  const int i0 = blockIdx.y * 64;
  const int j0 = blockIdx.x * 64;
  const int tx = t & 15, ty = t >> 4;
  float acc[4][4] = {};
  for (int u0 = 0; u0 < 1024; u0 += 32) {
    __syncthreads();
#pragma unroll
    for (int p = 0; p < 2; ++p) {
      int idx = p * 256 + t;
      int lu = idx >> 4, lc = (idx & 15) * 4;
      *(float4*)&w1[lu][lc] = *(const float4*)(W + (size_t)(u0 + lu) * 1024 + i0 + lc);
      *(float4*)&w2[lu][lc] = *(const float4*)(W + (size_t)(u0 + lu) * 1024 + j0 + lc);
    }
    __syncthreads();
#pragma unroll 8
    for (int u = 0; u < 32; ++u) {
      float4 a = *(const float4*)&w1[u][ty * 4];
      float4 b = *(const float4*)&w2[u][tx * 4];
      float av[4] = {a.x, a.y, a.z, a.w};
      float bv[4] = {b.x, b.y, b.z, b.w};
#pragma unroll
      for (int e = 0; e < 4; ++e)
#pragma unroll
        for (int f = 0; f < 4; ++f)
          acc[e][f] += av[e] * bv[f];
    }
  }
  const float s = 0.03125f;
#pragma unroll
  for (int e = 0; e < 4; ++e) {
    ushort4 v;
    v.x = f2bf(acc[e][0] * s);
    v.y = f2bf(acc[e][1] * s);
    v.z = f2bf(acc[e][2] * s);
    v.w = f2bf(acc[e][3] * s);
    *(ushort4*)(Mb + (size_t)(i0 + ty * 4 + e) * 1024 + j0 + tx * 4) = v;
  }
}

// ---------------- K2: 8-phase fused-cvt GEMM ----------------------------------
// vmcnt ledger (per-thread issue stream; A=4 loads even phases, B=2 odd):
//  steady odd-end VMC(6) keeps {A@this-even(4), B@this-odd(2)}; forces the
//  A-quad issued 3 phases ago (cvt'd next even phase) and the B-half staged
//  2 phases ago (read >=3 phases later). Prologue queue (22):
//  [A00 A01 B00 B01 B10 A10 A11] -> VMC(4) leaves A11 (forced at b0-f1 VMC(6)).
//  Tail b=7: f1 VMC(2) (forces A@b6f6 + B@b6f7), f3 VMC(0), f5/f7 none.
__global__ __launch_bounds__(512, 2) void gemm8p(const float* __restrict__ X,
                                                 const u16* __restrict__ Mb,
                                                 float* __restrict__ out) {
  __shared__ u16 lds[8 * 8192];  // 8 half-slots x 256 rows x 32 bf16 = 128 KB

  const int p = blockIdx.x;                  // nwg = 1024 (%8==0)
  const int wg = (p & 7) * 128 + (p >> 3);   // chunked XCD swizzle
  const int bm = wg >> 2;                    // 0..255
  const int bn = wg & 3;                     // 0..3 (A-panel shared by 4 on XCD)
  const size_t r0 = (size_t)bm * 256;
  const int c0 = bn * 256;

  const int t = threadIdx.x;
  const int lane = t & 63;
  const int w = t >> 6;
  const int wr = w >> 2, wc = w & 3;         // 2x4 wave grid, wave tile 128x64
  const int fr = lane & 15;
  const int kc = lane >> 4;

  const int srow = t >> 2;                   // 0..127
  const int scl = t & 3;
  const int csw = scl ^ ((srow >> 1) & 3);   // XOR chunk swizzle (involution)
  const float* aL = X + (r0 + srow) * 1024 + scl * 8;
  const float* aH = X + (r0 + 128 + srow) * 1024 + scl * 8;
  const u16* gB = Mb + (size_t)(c0 + srow) * 1024 + csw * 8;        // pre-swz src
  const u16* gB2 = Mb + (size_t)(c0 + 128 + srow) * 1024 + csw * 8;
  u16* wLp = lds + srow * 32 + csw * 8;      // swizzled A write (reg-staged)
  u16* wHp = wLp + 128 * 32;
  u16* bDst = lds + w * 512;                 // linear B dest (+slot*8192, +4096 hi)

  f32x4 acc[8][4] = {};
  f32x4 pend[2][4];
  f32x4 q0[4], q1[4];

  // ---- prologue ----
  load2x16(aL + 0, q0[0], q0[1]);   load2x16(aH + 0, q0[2], q0[3]);    // A kt0 kh0
  load2x16(aL + 32, q1[0], q1[1]);  load2x16(aH + 32, q1[2], q1[3]);   // A kt0 kh1
  gload_lds16(gB + 0, bDst + 1 * 8192);   gload_lds16(gB2 + 0, bDst + 1 * 8192 + 4096);
  gload_lds16(gB + 32, bDst + 3 * 8192);  gload_lds16(gB2 + 32, bDst + 3 * 8192 + 4096);
  gload_lds16(gB + 64, bDst + 5 * 8192);  gload_lds16(gB2 + 64, bDst + 5 * 8192 + 4096);
  load2x16(aL + 64, pend[0][0], pend[0][1]); load2x16(aH + 64, pend[0][2], pend[0][3]); // A kt1 kh0
  load2x16(aL + 96, pend[1][0], pend[1][1]); load2x16(aH + 96, pend[1][2], pend[1][3]); // A kt1 kh1
  VMC(4);  // forces A00,A01,B00,B01,B10,A10; leaves A11
  SCHED0();
  *(bf16x8*)(wLp + 0) = cvt8(q0[0], q0[1]);
  *(bf16x8*)(wHp + 0) = cvt8(q0[2], q0[3]);
  *(bf16x8*)(wLp + 2 * 8192) = cvt8(q1[0], q1[1]);
  *(bf16x8*)(wHp + 2 * 8192) = cvt8(q1[2], q1[3]);
  LGKM0(); SCHED0();
  BAR();

  for (int b = 0; b < 8; ++b) {
    const bool nl = (b < 7);
    bf16x8 bf[4];
#pragma unroll
    for (int f = 0; f < 8; ++f) {
      const int kh = (f >> 1) & 1;
      const int msub = f & 1;
      const int slotA = (f >> 2) * 4 + kh * 2;
      // ---- region 1: A cvt+write, ds_reads, issues/stages ----
      if (msub == 0) {
        const int wslot = (f == 0) ? 4 : (f == 2) ? 6 : (f == 4) ? 0 : 2;
        if (f < 4 || nl) {  // write pending set (issued 4 phases ago)
          *(bf16x8*)(wLp + wslot * 8192) = cvt8(pend[kh][0], pend[kh][1]);
          *(bf16x8*)(wHp + wslot * 8192) = cvt8(pend[kh][2], pend[kh][3]);
        }
      }
      bf16x8 af[4];
#pragma unroll
      for (int i = 0; i < 4; ++i) {
        const int row = wr * 128 + (msub * 4 + i) * 16 + fr;
        const int cs = kc ^ ((row >> 1) & 3);
        af[i] = *(const bf16x8*)&lds[slotA * 8192 + row * 32 + cs * 8];
      }
      if (msub == 0) {
#pragma unroll
        for (int n = 0; n < 4; ++n) {
          const int row = wc * 64 + n * 16 + fr;
          const int cs = kc ^ ((row >> 1) & 3);
          bf[n] = *(const bf16x8*)&lds[(slotA + 1) * 8192 + row * 32 + cs * 8];
        }
      }
      if (msub == 0 && nl) {  // A issue (written at phase f+4)
        const int koff = (2 * b + 2 + (f >> 2)) * 64 + kh * 32;
        load2x16(aL + koff, pend[kh][0], pend[kh][1]);
        load2x16(aH + koff, pend[kh][2], pend[kh][3]);
      }
      if (msub == 1) {  // B stage
        const int idx = f >> 1;  // 0..3
        if (idx == 0 || nl) {
          const int kadd = (idx == 0) ? 1 : (idx == 3) ? 3 : 2;
          const int khb = 1 - (idx & 1);
          const int slot_s = (idx == 0) ? 7 : 2 * idx - 1;
          const int koffb = (2 * b + kadd) * 64 + khb * 32;
          gload_lds16(gB + koffb, bDst + slot_s * 8192);
          gload_lds16(gB2 + koffb, bDst + slot_s * 8192 + 4096);
        }
      }
      BAR();
      LGKM0(); SCHED0();
      __builtin_amdgcn_s_setprio(1);
#pragma unroll
      for (int i = 0; i < 4; ++i)
#pragma unroll
        for (int n = 0; n < 4; ++n)
          acc[msub * 4 + i][n] = __builtin_amdgcn_mfma_f32_16x16x32_bf16(
              af[i], bf[n], acc[msub * 4 + i][n], 0, 0, 0);
      __builtin_amdgcn_s_setprio(0);
      if (msub == 1) {  // counted vmcnt BEFORE closing barrier (cross-wave safe)
        const int idx = f >> 1;
        if (nl) {
          VMC(6);
        } else if (idx == 0) {
          VMC(2);
        } else if (idx == 1) {
          VMC(0);
        }
        SCHED0();
      }
      BAR();
    }
  }

  // ---- epilogue: C layout col=lane&15, row=(lane>>4)*4+reg ----
  const int ocol = lane & 15;
  const int orow = (lane >> 4) * 4;
#pragma unroll
  for (int m = 0; m < 8; ++m) {
    const size_t rbase = (r0 + wr * 128 + m * 16 + orow) * 1024;
#pragma unroll
    for (int n = 0; n < 4; ++n) {
      float* o = out + rbase + (c0 + wc * 64 + n * 16 + ocol);
      o[0] = acc[m][n][0];
      o[1024] = acc[m][n][1];
      o[2048] = acc[m][n][2];
      o[3072] = acc[m][n][3];
    }
  }
}

extern "C" void kernel_launch(void* const* d_in, const int* in_sizes, int n_in,
                              void* d_out, int out_size, void* d_ws, size_t ws_size,
                              hipStream_t stream) {
  const float* X = (const float*)d_in[0];
  const float* W = (const float*)d_in[1];
  float* out = (float*)d_out;
  u16* Mb = (u16*)d_ws;  // 2 MB scratch

  compute_M<<<dim3(16, 16), 256, 0, stream>>>(W, Mb);
  gemm8p<<<1024, 512, 0, stream>>>(X, Mb, out);
}